// Round 10
// baseline (91.880 us; speedup 1.0000x reference)
//
#include <hip/hip_runtime.h>

// INP=4096 MSK=64 HID=64 OUT=10  L1=64 L2=256 L3=128  B=16384  WVEC=4810
// k_prep  : W1^T -> f16; W2/W3 -> f16; W4 -> f16 in MFMA fragment order
// k_front : 16 samples/block, grid 1024, high occupancy: idx -> xm gather ->
//           L1 dedup-sum -> L2/L3 f16 MFMA -> xm(f32)/h3(f16) to ws
// k_gemm  : 64 samples/block, grid 256: register-resident W4 GEMM (A stream
//           from L2 via fragment-ordered W4s) + fused per-sample einsums

typedef _Float16 f16;
typedef _Float16 f16x8 __attribute__((ext_vector_type(8)));
typedef _Float16 f16x4 __attribute__((ext_vector_type(4)));
typedef float    f32x4 __attribute__((ext_vector_type(4)));

#define NPAD 4864   // 4810 W4 rows padded to 76*64

// ---------------------------------------------------------------- prep
__global__ __launch_bounds__(256) void k_prep(
    const float* __restrict__ W1, const float* __restrict__ W2,
    const float* __restrict__ W3, const float* __restrict__ W4,
    f16* __restrict__ W1Th, f16* __restrict__ W2h,
    f16* __restrict__ W3h, f16* __restrict__ W4s)
{
    const int tid = blockIdx.x * 256 + threadIdx.x;
    const int stride = gridDim.x * 256;
    for (int e = tid; e < 4096 * 64; e += stride) {
        int j = e >> 6, i = e & 63;
        W1Th[e] = (f16)W1[(size_t)i * 4096 + j];
    }
    // fragment-ordered W4
    for (int e = tid; e < NPAD * 128; e += stride) {
        const int j    = e & 7;
        const int lane = (e >> 3) & 63;
        const int mt   = (e >> 9) & 3;
        const int kk   = (e >> 11) & 3;
        const int c    = e >> 13;
        const int lr = lane & 15, g = lane >> 4;
        const int row = 64 * c + 16 * mt + lr;
        const int col = 32 * kk + 8 * g + j;
        W4s[e] = (row < 4810) ? (f16)W4[(size_t)row * 128 + col] : (f16)0.f;
    }
    for (int e = tid; e < 256 * 64; e += stride)  W2h[e] = (f16)W2[e];
    for (int e = tid; e < 128 * 256; e += stride) W3h[e] = (f16)W3[e];
}

// ---------------------------------------------------------------- front
// 16 samples/block, 256 thr (4 waves), grid 1024.
// LDS: idx 4KB; h1 swz 2KB; h2 swz 8KB.
__global__ __launch_bounds__(256, 4) void k_front(
    const float* __restrict__ data, const int* __restrict__ midx,
    const f16* __restrict__ W1Th, const float* __restrict__ b1,
    const f16* __restrict__ W2h, const float* __restrict__ b2,
    const f16* __restrict__ W3h, const float* __restrict__ b3,
    float* __restrict__ xm_ws, f16* __restrict__ h3h)
{
    __shared__ __align__(16) int  idx_s[16 * 64];
    __shared__ __align__(16) char h1b[2048];
    __shared__ __align__(16) char h2b[8192];

    const int t = threadIdx.x, w = t >> 6, lane = t & 63;
    const int lr = lane & 15, g = lane >> 4;
    const int row0 = blockIdx.x * 16;
    const f32x4 zero = {0.f, 0.f, 0.f, 0.f};

    // ---- idx -> LDS
    for (int k = 0; k < 4; ++k)
        idx_s[k * 256 + t] = midx[(size_t)row0 * 64 + k * 256 + t];
    __syncthreads();

    // ---- issue xm random gather (4 loads/thread; drain under L1 phase)
    float xr[4];
    #pragma unroll
    for (int k = 0; k < 4; ++k) {
        const int e = k * 256 + t;           // e = s*64 + m
        xr[k] = data[(size_t)(row0 + (e >> 6)) * 4096 + idx_s[e]];
    }

    // ---- L1 dedup gather-sum (wave w: samples 4w..4w+3)
    {
        const f32x4 b1v = *(const f32x4*)&b1[lr * 4];
        #pragma unroll
        for (int p = 0; p < 2; ++p) {
            const int s0 = 4 * w + 2 * p, s1 = s0 + 1;
            f32x4 a0 = zero, a1 = zero;
            #pragma unroll
            for (int tt = 0; tt < 16; ++tt) {
                const int i = g * 16 + tt;
                const int c0 = idx_s[s0 * 64 + i];
                const int q0 = (i > 0) ? idx_s[s0 * 64 + i - 1] : -1;
                const int c1 = idx_s[s1 * 64 + i];
                const int q1 = (i > 0) ? idx_s[s1 * 64 + i - 1] : -1;
                const f16x4 w0 = *(const f16x4*)&W1Th[c0 * 64 + lr * 4];
                const f16x4 w1 = *(const f16x4*)&W1Th[c1 * 64 + lr * 4];
                #pragma unroll
                for (int q = 0; q < 4; ++q) {
                    a0[q] += (c0 != q0) ? (float)w0[q] : 0.f;
                    a1[q] += (c1 != q1) ? (float)w1[q] : 0.f;
                }
            }
            #pragma unroll
            for (int q = 0; q < 4; ++q) {
                a0[q] += __shfl_xor(a0[q], 16);
                a0[q] += __shfl_xor(a0[q], 32);
                a1[q] += __shfl_xor(a1[q], 16);
                a1[q] += __shfl_xor(a1[q], 32);
            }
            if (g == 0) {
                f16x4 h0, h1v;
                #pragma unroll
                for (int q = 0; q < 4; ++q) {
                    h0[q]  = (f16)fmaxf(a0[q] + b1v[q], 0.f);
                    h1v[q] = (f16)fmaxf(a1[q] + b1v[q], 0.f);
                }
                *(f16x4*)(h1b + ((s0 * 128 + lr * 8) ^ ((s0 & 7) << 4))) = h0;
                *(f16x4*)(h1b + ((s1 * 128 + lr * 8) ^ ((s1 & 7) << 4))) = h1v;
            }
        }
    }
    // write xm while h1 settles
    #pragma unroll
    for (int k = 0; k < 4; ++k) {
        const int e = k * 256 + t;
        xm_ws[(size_t)(row0 + (e >> 6)) * 64 + (e & 63)] = xr[k];
    }
    __syncthreads();

    // ---- L2: wave w owns n in [64w, 64w+64), K=64, 16-sample B tile
    {
        f16x8 a2[4][2], bh[2];
        #pragma unroll
        for (int mt = 0; mt < 4; ++mt)
            #pragma unroll
            for (int kk = 0; kk < 2; ++kk)
                a2[mt][kk] = *(const f16x8*)&W2h[(64 * w + 16 * mt + lr) * 64 + 32 * kk + 8 * g];
        #pragma unroll
        for (int kk = 0; kk < 2; ++kk)
            bh[kk] = *(const f16x8*)(h1b + ((lr * 128 + (32 * kk + 8 * g) * 2) ^ ((lr & 7) << 4)));

        f32x4 acc2[4];
        #pragma unroll
        for (int mt = 0; mt < 4; ++mt) {
            acc2[mt] = __builtin_amdgcn_mfma_f32_16x16x32_f16(a2[mt][0], bh[0], zero, 0, 0, 0);
            acc2[mt] = __builtin_amdgcn_mfma_f32_16x16x32_f16(a2[mt][1], bh[1], acc2[mt], 0, 0, 0);
        }
        #pragma unroll
        for (int mt = 0; mt < 4; ++mt) {
            const int n = 64 * w + 16 * mt + 4 * g;
            const f32x4 bv = *(const f32x4*)&b2[n];
            f16x4 hv;
            #pragma unroll
            for (int q = 0; q < 4; ++q)
                hv[q] = (f16)fmaxf(acc2[mt][q] + bv[q], 0.f);
            *(f16x4*)(h2b + ((lr * 512 + n * 2) ^ ((lr & 7) << 4))) = hv;
        }
    }
    __syncthreads();

    // ---- L3: wave w owns n in [32w, 32w+32), K=256 -> h3 to ws (global)
    {
        f32x4 acc3[2] = {zero, zero};
        #pragma unroll 2
        for (int kk = 0; kk < 8; ++kk) {
            const f16x8 bb = *(const f16x8*)(h2b + ((lr * 512 + (32 * kk + 8 * g) * 2) ^ ((lr & 7) << 4)));
            #pragma unroll
            for (int mt = 0; mt < 2; ++mt) {
                const f16x8 a3 = *(const f16x8*)&W3h[(32 * w + 16 * mt + lr) * 256 + 32 * kk + 8 * g];
                acc3[mt] = __builtin_amdgcn_mfma_f32_16x16x32_f16(a3, bb, acc3[mt], 0, 0, 0);
            }
        }
        #pragma unroll
        for (int mt = 0; mt < 2; ++mt) {
            const int n = 32 * w + 16 * mt + 4 * g;
            const f32x4 bv3 = *(const f32x4*)&b3[n];
            f16x4 hv;
            #pragma unroll
            for (int q = 0; q < 4; ++q)
                hv[q] = (f16)fmaxf(acc3[mt][q] + bv3[q], 0.f);
            *(f16x4*)&h3h[(size_t)(row0 + lr) * 128 + n] = hv;
        }
    }
}

// ---------------------------------------------------------------- gemm
// 64 samples/block, 512 thr (8 waves), grid 256.
// LDS: hid[64][68]f32 17.4KB + res[64][12]f32 3KB.
__global__ __launch_bounds__(512, 2) void k_gemm(
    const float* __restrict__ xm_ws, const f16* __restrict__ h3h,
    const f16* __restrict__ W4s, const float* __restrict__ b4,
    float* __restrict__ out)
{
    __shared__ __align__(16) float hid_s[64 * 68];
    __shared__ __align__(16) float res_s[64 * 12];

    const int t = threadIdx.x, w = t >> 6, lane = t & 63;
    const int lr = lane & 15, g = lane >> 4;
    const int row0 = blockIdx.x * 64;
    const f32x4 zero = {0.f, 0.f, 0.f, 0.f};

    // B-fragments for all 64 samples (4 u-sets) from global h3
    f16x8 bfrag[4][4];                     // [kk][u]
    #pragma unroll
    for (int u = 0; u < 4; ++u)
        #pragma unroll
        for (int kk = 0; kk < 4; ++kk)
            bfrag[kk][u] = *(const f16x8*)&h3h[(size_t)(row0 + 16 * u + lr) * 128 + 32 * kk + 8 * g];

    // xm packed f16 registers
    f16x4 xmr[4][4];                       // [mt][u]
    #pragma unroll
    for (int mt = 0; mt < 4; ++mt)
        #pragma unroll
        for (int u = 0; u < 4; ++u) {
            const f32x4 xv = *(const f32x4*)&xm_ws[(size_t)(row0 + 16 * u + lr) * 64 + 16 * mt + 4 * g];
            f16x4 xh;
            #pragma unroll
            for (int q = 0; q < 4; ++q) xh[q] = (f16)xv[q];
            xmr[mt][u] = xh;
        }

    const char* W4b = (const char*)W4s;
    const int afoff = lane * 16;

#define LDAF(dst, c, kk) { const char* cb_ = W4b + (size_t)(c) * 16384 + (kk) * 4096 + afoff; \
    dst[0] = *(const f16x8*)(cb_);        dst[1] = *(const f16x8*)(cb_ + 1024); \
    dst[2] = *(const f16x8*)(cb_ + 2048); dst[3] = *(const f16x8*)(cb_ + 3072); }

#define MFMA16(af, kk) { \
    _Pragma("unroll") for (int mt = 0; mt < 4; ++mt) \
    _Pragma("unroll") for (int u = 0; u < 4; ++u) \
        acc[mt][u] = __builtin_amdgcn_mfma_f32_16x16x32_f16(af[mt], bfrag[kk][u], acc[mt][u], 0, 0, 0); }

    // ---- inp_w chunks: wave w -> c = w, w+8, ..., w+56
    {
        f16x8 afA[4], afB[4];
        LDAF(afA, w, 0)
        for (int i = 0; i < 8; ++i) {
            const int c = 8 * i + w;
            f32x4 bv[4];
            #pragma unroll
            for (int mt = 0; mt < 4; ++mt)
                bv[mt] = *(const f32x4*)&b4[64 * c + 16 * mt + 4 * g];
            LDAF(afB, c, 1)
            f32x4 acc[4][4];
            #pragma unroll
            for (int mt = 0; mt < 4; ++mt)
                #pragma unroll
                for (int u = 0; u < 4; ++u)
                    acc[mt][u] = __builtin_amdgcn_mfma_f32_16x16x32_f16(afA[mt], bfrag[0][u], zero, 0, 0, 0);
            LDAF(afA, c, 2)
            MFMA16(afB, 1)
            LDAF(afB, c, 3)
            MFMA16(afA, 2)
            if (i < 7) { LDAF(afA, 8 * (i + 1) + w, 0) }
            MFMA16(afB, 3)

            #pragma unroll
            for (int u = 0; u < 4; ++u) {
                float sum = 0.f;
                #pragma unroll
                for (int mt = 0; mt < 4; ++mt)
                    #pragma unroll
                    for (int q = 0; q < 4; ++q)
                        sum += (acc[mt][u][q] + bv[mt][q]) * (float)xmr[mt][u][q];
                sum += __shfl_xor(sum, 16);
                sum += __shfl_xor(sum, 32);
                if (g == 0) hid_s[(16 * u + lr) * 68 + c] = sum;
            }
        }
    }

    // ---- chunk 64 (inp_b): waves 0..3 handle mt=w; compute before barrier
    f32x4 acc64[4] = {zero, zero, zero, zero};
    if (w < 4) {
        f16x8 af64[4];
        #pragma unroll
        for (int kk = 0; kk < 4; ++kk)
            af64[kk] = *(const f16x8*)(W4b + (size_t)64 * 16384 + kk * 4096 + w * 1024 + afoff);
        #pragma unroll
        for (int kk = 0; kk < 4; ++kk)
            #pragma unroll
            for (int u = 0; u < 4; ++u)
                acc64[u] = __builtin_amdgcn_mfma_f32_16x16x32_f16(af64[kk], bfrag[kk][u], acc64[u], 0, 0, 0);
    }
    __syncthreads();                       // all inp hid writes done
    if (w < 4) {
        const f32x4 bv64 = *(const f32x4*)&b4[4096 + 16 * w + 4 * g];
        #pragma unroll
        for (int u = 0; u < 4; ++u) {
            float* hp = &hid_s[(16 * u + lr) * 68 + 16 * w + 4 * g];
            f32x4 hv = *(const f32x4*)hp;
            #pragma unroll
            for (int q = 0; q < 4; ++q)
                hv[q] = hv[q] + acc64[u][q] + bv64[q];
            *(f32x4*)hp = hv;
        }
    }
    __syncthreads();
    // ReLU hid
    for (int e = t; e < 4096; e += 512) {
        const int si = e >> 6, h = e & 63;
        hid_s[si * 68 + h] = fmaxf(hid_s[si * 68 + h], 0.f);
    }
    __syncthreads();
    // hid packed f16 registers (reuse xmr storage)
    #pragma unroll
    for (int mt = 0; mt < 4; ++mt)
        #pragma unroll
        for (int u = 0; u < 4; ++u) {
            const f32x4 hv = *(const f32x4*)&hid_s[(16 * u + lr) * 68 + 16 * mt + 4 * g];
            f16x4 xh;
            #pragma unroll
            for (int q = 0; q < 4; ++q) xh[q] = (f16)hv[q];
            xmr[mt][u] = xh;
        }

    // ---- out_w chunks 65..74: wave w -> 65+w; waves 6,7 also 73,74
    auto do_out = [&](int c) {
        f32x4 bv[4];
        #pragma unroll
        for (int mt = 0; mt < 4; ++mt)
            bv[mt] = *(const f32x4*)&b4[64 * c + 16 * mt + 4 * g];
        f16x8 afA[4], afB[4];
        LDAF(afA, c, 0)
        LDAF(afB, c, 1)
        f32x4 acc[4][4];
        #pragma unroll
        for (int mt = 0; mt < 4; ++mt)
            #pragma unroll
            for (int u = 0; u < 4; ++u)
                acc[mt][u] = __builtin_amdgcn_mfma_f32_16x16x32_f16(afA[mt], bfrag[0][u], zero, 0, 0, 0);
        LDAF(afA, c, 2)
        MFMA16(afB, 1)
        LDAF(afB, c, 3)
        MFMA16(afA, 2)
        MFMA16(afB, 3)
        #pragma unroll
        for (int u = 0; u < 4; ++u) {
            float sum = 0.f;
            #pragma unroll
            for (int mt = 0; mt < 4; ++mt)
                #pragma unroll
                for (int q = 0; q < 4; ++q)
                    sum += (acc[mt][u][q] + bv[mt][q]) * (float)xmr[mt][u][q];
            sum += __shfl_xor(sum, 16);
            sum += __shfl_xor(sum, 32);
            if (g == 0) res_s[(16 * u + lr) * 12 + (c - 65)] = sum;
        }
    };
    do_out(65 + w);
    if (w >= 6) do_out(67 + w);            // 73, 74

    // ---- chunk 75 (out_b rows 4800..4809): wave 4 computes
    f32x4 acc75[4] = {zero, zero, zero, zero};
    if (w == 4) {
        f16x8 af75[4];
        #pragma unroll
        for (int kk = 0; kk < 4; ++kk)
            af75[kk] = *(const f16x8*)(W4b + (size_t)75 * 16384 + kk * 4096 + afoff);
        #pragma unroll
        for (int kk = 0; kk < 4; ++kk)
            #pragma unroll
            for (int u = 0; u < 4; ++u)
                acc75[u] = __builtin_amdgcn_mfma_f32_16x16x32_f16(af75[kk], bfrag[kk][u], acc75[u], 0, 0, 0);
    }
    __syncthreads();                       // all out_w res writes done
    if (w == 4) {
        #pragma unroll
        for (int u = 0; u < 4; ++u)
            #pragma unroll
            for (int q = 0; q < 4; ++q) {
                const int o = 4 * g + q;
                if (o < 10)
                    res_s[(16 * u + lr) * 12 + o] += acc75[u][q] + b4[4800 + o];
            }
    }
    __syncthreads();

    for (int e = t; e < 640; e += 512)
        out[(size_t)row0 * 10 + e] = res_s[(e / 10) * 12 + (e % 10)];
#undef LDAF
#undef MFMA16
}

// ---------------------------------------------------------------- launcher
extern "C" void kernel_launch(void* const* d_in, const int* in_sizes, int n_in,
                              void* d_out, int out_size, void* d_ws, size_t ws_size,
                              hipStream_t stream)
{
    const float* data = (const float*)d_in[0];
    const int*   midx = (const int*)d_in[1];
    const float* W1   = (const float*)d_in[2];
    const float* b1   = (const float*)d_in[3];
    const float* W2   = (const float*)d_in[4];
    const float* b2   = (const float*)d_in[5];
    const float* W3   = (const float*)d_in[6];
    const float* b3   = (const float*)d_in[7];
    const float* W4   = (const float*)d_in[8];
    const float* b4   = (const float*)d_in[9];
    float* out = (float*)d_out;

    float* xm_ws = (float*)d_ws;                        // 1048576 f32
    f16*   W1Th  = (f16*)(xm_ws + (size_t)16384 * 64);  // 262144 f16
    f16*   W4s   = W1Th + (size_t)4096 * 64;            // 622592 f16
    f16*   W2h   = W4s + (size_t)NPAD * 128;            // 16384 f16
    f16*   W3h   = W2h + 256 * 64;                      // 32768 f16
    f16*   h3h   = W3h + 128 * 256;                     // 2097152 f16

    k_prep <<<512, 256, 0, stream>>>(W1, W2, W3, W4, W1Th, W2h, W3h, W4s);
    k_front<<<1024, 256, 0, stream>>>(data, midx, W1Th, b1, W2h, b2, W3h, b3,
                                      xm_ws, h3h);
    k_gemm <<<256, 512, 0, stream>>>(xm_ws, h3h, W4s, b4, out);
}

// Round 11
// 74.714 us; speedup vs baseline: 1.2298x; 1.2298x over previous
//
#include <hip/hip_runtime.h>

// INP=4096 MSK=64 HID=64 OUT=10  L1=64 L2=256 L3=128  B=16384  WVEC=4810
// k_prep : W1^T -> f16; W2/W3 -> f16; W4 -> f16 in MFMA fragment order
// k_main : grid 256 x 512 thr. WAVE-SPECIALIZED:
//   wave 7  = gather producer: issues all 64 xm random-load instrs at t~0,
//             parks at RAW barriers (no vmcnt drain!), drains + writes xm_s
//             just before the xm-barrier, then joins the GEMM.
//   waves 0-6 = front: L1 dedup-sum, L2/L3 f16 MFMA under the gather.
//   then all 8 waves: register-resident W4 GEMM (fragment-ordered A stream
//   from L2, 4 MFMA per A-load) + fused per-sample einsum epilogues.
// All barriers are raw (lgkmcnt(0)+s_barrier): cross-wave data is LDS-only.

typedef _Float16 f16;
typedef _Float16 f16x8 __attribute__((ext_vector_type(8)));
typedef _Float16 f16x4 __attribute__((ext_vector_type(4)));
typedef float    f32x4 __attribute__((ext_vector_type(4)));

#define NPAD 4864   // 4810 W4 rows padded to 76*64

#define BAR() do { asm volatile("s_waitcnt lgkmcnt(0)" ::: "memory"); \
                   __builtin_amdgcn_s_barrier();                      \
                   asm volatile("" ::: "memory"); } while (0)

// ---------------------------------------------------------------- prep
__global__ __launch_bounds__(256) void k_prep(
    const float* __restrict__ W1, const float* __restrict__ W2,
    const float* __restrict__ W3, const float* __restrict__ W4,
    f16* __restrict__ W1Th, f16* __restrict__ W2h,
    f16* __restrict__ W3h, f16* __restrict__ W4s)
{
    const int tid = blockIdx.x * 256 + threadIdx.x;
    const int stride = gridDim.x * 256;
    for (int e = tid; e < 4096 * 64; e += stride) {
        int j = e >> 6, i = e & 63;
        W1Th[e] = (f16)W1[(size_t)i * 4096 + j];
    }
    for (int e = tid; e < NPAD * 128; e += stride) {
        const int j    = e & 7;
        const int lane = (e >> 3) & 63;
        const int mt   = (e >> 9) & 3;
        const int kk   = (e >> 11) & 3;
        const int c    = e >> 13;
        const int lr = lane & 15, g = lane >> 4;
        const int row = 64 * c + 16 * mt + lr;
        const int col = 32 * kk + 8 * g + j;
        W4s[e] = (row < 4810) ? (f16)W4[(size_t)row * 128 + col] : (f16)0.f;
    }
    for (int e = tid; e < 256 * 64; e += stride)  W2h[e] = (f16)W2[e];
    for (int e = tid; e < 128 * 256; e += stride) W3h[e] = (f16)W3[e];
}

// ---------------------------------------------------------------- main
__global__ __launch_bounds__(512, 2) void k_main(
    const float* __restrict__ data, const int* __restrict__ midx,
    const f16* __restrict__ W1Th, const float* __restrict__ b1,
    const f16* __restrict__ W2h, const float* __restrict__ b2,
    const f16* __restrict__ W3h, const float* __restrict__ b3,
    const f16* __restrict__ W4s, const float* __restrict__ b4,
    float* __restrict__ out)
{
    __shared__ __align__(16) int   idx_s[64 * 64];    // 16 KB
    __shared__ __align__(16) char  h1b[8192];         // h1 f16 swz
    __shared__ __align__(16) char  h2b[32768];        // h2 f16 swz
    __shared__ __align__(16) char  h3b[16384];        // h3 f16 swz
    __shared__ __align__(16) float xm_s[64 * 68];     // 17.4 KB
    __shared__ __align__(16) float hid_s[64 * 68];    // 17.4 KB
    __shared__ __align__(16) f16   w64_s[64 * 64];    // 8 KB (inp_b tile)
    __shared__ __align__(16) float res_s[64 * 12];    // 3 KB
    __shared__ __align__(16) float res_b[64 * 12];    // 3 KB (out_b tile)

    const int t = threadIdx.x, w = t >> 6, lane = t & 63;
    const int lr = lane & 15, g = lane >> 4;
    const int row0 = blockIdx.x * 64;
    const f32x4 zero = {0.f, 0.f, 0.f, 0.f};

    // ---- stage idx (all waves; wave 7's loads retire before its gathers)
    for (int e = t; e < 4096; e += 512)
        idx_s[e] = midx[(size_t)row0 * 64 + e];
    BAR();                                   // B0: idx ready

    float xr[64];                            // live only on wave-7 path

    if (w == 7) {
        // ---- issue ALL 64 gather instrs; keep them outstanding across
        // the raw barriers (no other vector loads in this wave's stream).
        #pragma unroll
        for (int k = 0; k < 64; ++k)
            xr[k] = data[(size_t)(row0 + k) * 4096 + idx_s[k * 64 + lane]];
        __builtin_amdgcn_sched_barrier(0);
    } else {
        // ---- L1 dedup gather-sum: sample-pairs sp = w, w+7, ... (<32)
        const f32x4 b1v = *(const f32x4*)&b1[lr * 4];
        for (int sp = w; sp < 32; sp += 7) {
            const int s0 = 2 * sp, s1 = s0 + 1;
            f32x4 a0 = zero, a1 = zero;
            #pragma unroll
            for (int tt = 0; tt < 16; ++tt) {
                const int i = g * 16 + tt;
                const int c0 = idx_s[s0 * 64 + i];
                const int q0 = (i > 0) ? idx_s[s0 * 64 + i - 1] : -1;
                const int c1 = idx_s[s1 * 64 + i];
                const int q1 = (i > 0) ? idx_s[s1 * 64 + i - 1] : -1;
                const f16x4 w0 = *(const f16x4*)&W1Th[c0 * 64 + lr * 4];
                const f16x4 w1 = *(const f16x4*)&W1Th[c1 * 64 + lr * 4];
                #pragma unroll
                for (int q = 0; q < 4; ++q) {
                    a0[q] += (c0 != q0) ? (float)w0[q] : 0.f;
                    a1[q] += (c1 != q1) ? (float)w1[q] : 0.f;
                }
            }
            #pragma unroll
            for (int q = 0; q < 4; ++q) {
                a0[q] += __shfl_xor(a0[q], 16);
                a0[q] += __shfl_xor(a0[q], 32);
                a1[q] += __shfl_xor(a1[q], 16);
                a1[q] += __shfl_xor(a1[q], 32);
            }
            if (g == 0) {
                f16x4 h0, h1v;
                #pragma unroll
                for (int q = 0; q < 4; ++q) {
                    h0[q]  = (f16)fmaxf(a0[q] + b1v[q], 0.f);
                    h1v[q] = (f16)fmaxf(a1[q] + b1v[q], 0.f);
                }
                *(f16x4*)(h1b + ((s0 * 128 + lr * 8) ^ ((s0 & 7) << 4))) = h0;
                *(f16x4*)(h1b + ((s1 * 128 + lr * 8) ^ ((s1 & 7) << 4))) = h1v;
            }
        }
    }
    BAR();                                   // B1: h1 ready

    if (w < 7) {
        // ---- L2: n-blocks of 32, nb = w, w+7
        f16x8 bh[4][2];
        #pragma unroll
        for (int rt = 0; rt < 4; ++rt)
            #pragma unroll
            for (int kk = 0; kk < 2; ++kk) {
                const int s = 16 * rt + lr;
                bh[rt][kk] = *(const f16x8*)(h1b + ((s * 128 + (32 * kk + 8 * g) * 2) ^ ((s & 7) << 4)));
            }
        for (int nb = w; nb < 8; nb += 7) {
            const int n0 = 32 * nb;
            f16x8 a2[2][2];
            #pragma unroll
            for (int mt = 0; mt < 2; ++mt)
                #pragma unroll
                for (int kk = 0; kk < 2; ++kk)
                    a2[mt][kk] = *(const f16x8*)&W2h[(n0 + 16 * mt + lr) * 64 + 32 * kk + 8 * g];
            f32x4 acc2[2][4];
            #pragma unroll
            for (int mt = 0; mt < 2; ++mt)
                #pragma unroll
                for (int rt = 0; rt < 4; ++rt) {
                    acc2[mt][rt] = __builtin_amdgcn_mfma_f32_16x16x32_f16(a2[mt][0], bh[rt][0], zero, 0, 0, 0);
                    acc2[mt][rt] = __builtin_amdgcn_mfma_f32_16x16x32_f16(a2[mt][1], bh[rt][1], acc2[mt][rt], 0, 0, 0);
                }
            #pragma unroll
            for (int mt = 0; mt < 2; ++mt) {
                const f32x4 bv = *(const f32x4*)&b2[n0 + 16 * mt + 4 * g];
                #pragma unroll
                for (int rt = 0; rt < 4; ++rt) {
                    const int s = 16 * rt + lr;
                    f16x4 hv;
                    #pragma unroll
                    for (int q = 0; q < 4; ++q)
                        hv[q] = (f16)fmaxf(acc2[mt][rt][q] + bv[q], 0.f);
                    *(f16x4*)(h2b + ((s * 512 + (n0 + 16 * mt + 4 * g) * 2) ^ ((s & 7) << 4))) = hv;
                }
            }
        }
    }
    BAR();                                   // B2: h2 ready

    if (w < 7) {
        // ---- L3: n-blocks of 16, nb = w, w+7
        for (int nb = w; nb < 8; nb += 7) {
            const int n0 = 16 * nb;
            f32x4 acc3[4] = {zero, zero, zero, zero};
            #pragma unroll 2
            for (int kk = 0; kk < 8; ++kk) {
                const f16x8 a3 = *(const f16x8*)&W3h[(n0 + lr) * 256 + 32 * kk + 8 * g];
                #pragma unroll
                for (int rt = 0; rt < 4; ++rt) {
                    const int s = 16 * rt + lr;
                    const f16x8 bb = *(const f16x8*)(h2b + ((s * 512 + (32 * kk + 8 * g) * 2) ^ ((s & 7) << 4)));
                    acc3[rt] = __builtin_amdgcn_mfma_f32_16x16x32_f16(a3, bb, acc3[rt], 0, 0, 0);
                }
            }
            const f32x4 bv3 = *(const f32x4*)&b3[n0 + 4 * g];
            #pragma unroll
            for (int rt = 0; rt < 4; ++rt) {
                const int s = 16 * rt + lr;
                f16x4 hv;
                #pragma unroll
                for (int q = 0; q < 4; ++q)
                    hv[q] = (f16)fmaxf(acc3[rt][q] + bv3[q], 0.f);
                *(f16x4*)(h3b + ((s * 256 + (n0 + 4 * g) * 2) ^ ((s & 7) << 4))) = hv;
            }
        }
    }
    BAR();                                   // B3: h3 ready

    // ---- all waves: B-fragments for all 64 samples
    f16x8 bfrag[4][4];                       // [kk][u]
    #pragma unroll
    for (int u = 0; u < 4; ++u)
        #pragma unroll
        for (int kk = 0; kk < 4; ++kk) {
            const int s = 16 * u + lr;
            bfrag[kk][u] = *(const f16x8*)(h3b + ((s * 256 + (32 * kk + 8 * g) * 2) ^ ((s & 7) << 4)));
        }
    if (w == 7) {
        // drain gathers (compiler inserts minimal in-order vmcnt) -> xm_s
        #pragma unroll
        for (int k = 0; k < 64; ++k)
            xm_s[k * 68 + lane] = xr[k];
    }
    BAR();                                   // B4: xm ready

    // xm packed f16 registers
    f16x4 xmr[4][4];                         // [mt][u]
    #pragma unroll
    for (int mt = 0; mt < 4; ++mt)
        #pragma unroll
        for (int u = 0; u < 4; ++u) {
            const f32x4 xv = *(const f32x4*)&xm_s[(16 * u + lr) * 68 + 16 * mt + 4 * g];
            f16x4 xh;
            #pragma unroll
            for (int q = 0; q < 4; ++q) xh[q] = (f16)xv[q];
            xmr[mt][u] = xh;
        }

    const char* W4b = (const char*)W4s;
    const int afoff = lane * 16;

#define LDAF(dst, c, kk) { const char* cb_ = W4b + (size_t)(c) * 16384 + (kk) * 4096 + afoff; \
    dst[0] = *(const f16x8*)(cb_);        dst[1] = *(const f16x8*)(cb_ + 1024); \
    dst[2] = *(const f16x8*)(cb_ + 2048); dst[3] = *(const f16x8*)(cb_ + 3072); }

#define MFMA16(af, kk) { \
    _Pragma("unroll") for (int mt = 0; mt < 4; ++mt) \
    _Pragma("unroll") for (int u = 0; u < 4; ++u) \
        acc[mt][u] = __builtin_amdgcn_mfma_f32_16x16x32_f16(af[mt], bfrag[kk][u], acc[mt][u], 0, 0, 0); }

    // ---- inp chunks 0..64 (8 waves): c = w, w+8, ...
    for (int c = w; c < 65; c += 8) {
        f16x8 afA[4], afB[4];
        LDAF(afA, c, 0)
        LDAF(afB, c, 1)
        f32x4 acc[4][4];
        #pragma unroll
        for (int mt = 0; mt < 4; ++mt)
            #pragma unroll
            for (int u = 0; u < 4; ++u)
                acc[mt][u] = __builtin_amdgcn_mfma_f32_16x16x32_f16(afA[mt], bfrag[0][u], zero, 0, 0, 0);
        LDAF(afA, c, 2)
        MFMA16(afB, 1)
        LDAF(afB, c, 3)
        MFMA16(afA, 2)
        MFMA16(afB, 3)

        f32x4 bv[4];
        #pragma unroll
        for (int mt = 0; mt < 4; ++mt)
            bv[mt] = *(const f32x4*)&b4[64 * c + 16 * mt + 4 * g];

        if (c < 64) {                        // inp_w: dot with xm -> hid_s
            #pragma unroll
            for (int u = 0; u < 4; ++u) {
                float sum = 0.f;
                #pragma unroll
                for (int mt = 0; mt < 4; ++mt)
                    #pragma unroll
                    for (int q = 0; q < 4; ++q)
                        sum += (acc[mt][u][q] + bv[mt][q]) * (float)xmr[mt][u][q];
                sum += __shfl_xor(sum, 16);
                sum += __shfl_xor(sum, 32);
                if (g == 0) hid_s[(16 * u + lr) * 68 + c] = sum;
            }
        } else {                             // inp_b tile -> w64_s (f16)
            #pragma unroll
            for (int u = 0; u < 4; ++u)
                #pragma unroll
                for (int mt = 0; mt < 4; ++mt) {
                    f16x4 wv;
                    #pragma unroll
                    for (int q = 0; q < 4; ++q)
                        wv[q] = (f16)(acc[mt][u][q] + bv[mt][q]);
                    *(f16x4*)&w64_s[(16 * u + lr) * 64 + 16 * mt + 4 * g] = wv;
                }
        }
    }
    BAR();                                   // B5: hid dots + w64 done

    // ---- hid registers with fused inp_b add + ReLU
    f16x4 hidr[4][4];                        // [mt][u]
    #pragma unroll
    for (int mt = 0; mt < 4; ++mt)
        #pragma unroll
        for (int u = 0; u < 4; ++u) {
            const int s = 16 * u + lr;
            f16x4 xh;
            #pragma unroll
            for (int q = 0; q < 4; ++q) {
                const int h = 16 * mt + 4 * g + q;
                xh[q] = (f16)fmaxf(hid_s[s * 68 + h] + (float)w64_s[s * 64 + h], 0.f);
            }
            hidr[mt][u] = xh;
        }

    // ---- out chunks 65..74: wave w -> 65+w; waves 0,1 also 73,74
    auto do_out = [&](int c) {
        f32x4 bv[4];
        #pragma unroll
        for (int mt = 0; mt < 4; ++mt)
            bv[mt] = *(const f32x4*)&b4[64 * c + 16 * mt + 4 * g];
        f16x8 afA[4], afB[4];
        LDAF(afA, c, 0)
        LDAF(afB, c, 1)
        f32x4 acc[4][4];
        #pragma unroll
        for (int mt = 0; mt < 4; ++mt)
            #pragma unroll
            for (int u = 0; u < 4; ++u)
                acc[mt][u] = __builtin_amdgcn_mfma_f32_16x16x32_f16(afA[mt], bfrag[0][u], zero, 0, 0, 0);
        LDAF(afA, c, 2)
        MFMA16(afB, 1)
        LDAF(afB, c, 3)
        MFMA16(afA, 2)
        MFMA16(afB, 3)
        #pragma unroll
        for (int u = 0; u < 4; ++u) {
            float sum = 0.f;
            #pragma unroll
            for (int mt = 0; mt < 4; ++mt)
                #pragma unroll
                for (int q = 0; q < 4; ++q)
                    sum += (acc[mt][u][q] + bv[mt][q]) * (float)hidr[mt][u][q];
            sum += __shfl_xor(sum, 16);
            sum += __shfl_xor(sum, 32);
            if (g == 0) res_s[(16 * u + lr) * 12 + (c - 65)] = sum;
        }
    };
    do_out(65 + w);
    if (w < 2) do_out(73 + w);

    // ---- chunk 75 (out_b rows 4800..4809): wave 2 -> res_b
    if (w == 2) {
        f32x4 accb[4] = {zero, zero, zero, zero};
        #pragma unroll
        for (int kk = 0; kk < 4; ++kk) {
            const f16x8 af = *(const f16x8*)(W4b + (size_t)75 * 16384 + kk * 4096 + afoff);
            #pragma unroll
            for (int u = 0; u < 4; ++u)
                accb[u] = __builtin_amdgcn_mfma_f32_16x16x32_f16(af, bfrag[kk][u], accb[u], 0, 0, 0);
        }
        #pragma unroll
        for (int u = 0; u < 4; ++u)
            #pragma unroll
            for (int q = 0; q < 4; ++q) {
                const int o = 4 * g + q;
                if (o < 10)
                    res_b[(16 * u + lr) * 12 + o] = accb[u][q] + b4[4800 + o];
            }
    }
    BAR();                                   // B6: res ready

    for (int e = t; e < 640; e += 512)
        out[(size_t)row0 * 10 + e] =
            res_s[(e / 10) * 12 + (e % 10)] + res_b[(e / 10) * 12 + (e % 10)];
#undef LDAF
#undef MFMA16
}

// ---------------------------------------------------------------- launcher
extern "C" void kernel_launch(void* const* d_in, const int* in_sizes, int n_in,
                              void* d_out, int out_size, void* d_ws, size_t ws_size,
                              hipStream_t stream)
{
    const float* data = (const float*)d_in[0];
    const int*   midx = (const int*)d_in[1];
    const float* W1   = (const float*)d_in[2];
    const float* b1   = (const float*)d_in[3];
    const float* W2   = (const float*)d_in[4];
    const float* b2   = (const float*)d_in[5];
    const float* W3   = (const float*)d_in[6];
    const float* b3   = (const float*)d_in[7];
    const float* W4   = (const float*)d_in[8];
    const float* b4   = (const float*)d_in[9];
    float* out = (float*)d_out;

    f16* W1Th = (f16*)d_ws;                    // 262144 f16
    f16* W4s  = W1Th + (size_t)4096 * 64;      // 622592 f16 (fragment-ordered)
    f16* W2h  = W4s + (size_t)NPAD * 128;      // 16384 f16
    f16* W3h  = W2h + 256 * 64;                // 32768 f16

    k_prep<<<512, 256, 0, stream>>>(W1, W2, W3, W4, W1Th, W2h, W3h, W4s);
    k_main<<<256, 512, 0, stream>>>(data, midx, W1Th, b1, W2h, b2, W3h, b3,
                                    W4s, b4, out);
}